// Round 1
// baseline (20336.789 us; speedup 1.0000x reference)
//
#include <hip/hip_runtime.h>
#include <hip/hip_bf16.h>

// Problem constants (fixed by setup_inputs)
constexpr int B_ = 8;
constexpr int C_ = 64;      // input channels = KC = VC = 64
constexpr int N_ = 65536;   // H*W = 256*256
constexpr int HW_ = 256;
constexpr float EPSF = 1e-6f;
constexpr int STATS = 4224; // 4096 matrix + 64 ksum + 64 vsum
constexpr int CHUNKS = 64;  // stats blocks per (branch,batch)

// ---------------- helpers for cat-buffer dtype ----------------
__device__ __forceinline__ float cat_ld(const float v) { return v; }
__device__ __forceinline__ float cat_ld(const __hip_bfloat16 v) { return __bfloat162float(v); }
__device__ __forceinline__ void cat_st(float* p, float v) { *p = v; }
__device__ __forceinline__ void cat_st(__hip_bfloat16* p, float v) { *p = __float2bfloat16(v); }

// ================================================================
// Pass 1: per (branch,batch,chunk) compute partial Ksum/Vsum/matrix.
// 256 threads. Tile = 64 pixels. Each thread: 16 channels x 1 pixel.
// LDS: kwT/vwT [c][m] stride 68 (transposed weights, broadcast reads),
//      Kt/Vt  [p][m] stride 68 (float4-aligned, conflict-free).
// ================================================================
__global__ __launch_bounds__(256, 2) void stats_kernel(
    const float* __restrict__ t1, const float* __restrict__ t2,
    const float* __restrict__ k1w, const float* __restrict__ k1b,
    const float* __restrict__ v1w, const float* __restrict__ v1b,
    const float* __restrict__ k2w, const float* __restrict__ k2b,
    const float* __restrict__ v2w, const float* __restrict__ v2b,
    float* __restrict__ partials)   // [2*B][CHUNKS][STATS]
{
  const int chunk = blockIdx.x;
  const int b = blockIdx.y;
  const int r = blockIdx.z;
  const float* x  = (r ? t2 : t1) + (size_t)b * C_ * N_;
  const float* kw = r ? k2w : k1w;
  const float* kb = r ? k2b : k1b;
  const float* vw = r ? v2w : v1w;
  const float* vb = r ? v2b : v1b;

  __shared__ float kwT[64 * 68];
  __shared__ float vwT[64 * 68];
  __shared__ float Kt[64 * 68];
  __shared__ float Vt[64 * 68];
  __shared__ float kb_s[64], vb_s[64];

  const int t = threadIdx.x;
  for (int idx = t; idx < 4096; idx += 256) {
    int m = idx >> 6, c = idx & 63;
    kwT[c * 68 + m] = kw[idx];
    vwT[c * 68 + m] = vw[idx];
  }
  if (t < 64) { kb_s[t] = kb[t]; vb_s[t] = vb[t]; }
  __syncthreads();

  const int mg = t & 3;       // channel group: channels mg*16 .. +16
  const int p  = t >> 2;      // pixel within tile (0..63)
  const int ty4 = (t >> 4) * 4;  // matrix-stage row base
  const int tx4 = (t & 15) * 4;  // matrix-stage col base

  float macc[16];
  float ksum[16], vsum[16];
#pragma unroll
  for (int i = 0; i < 16; ++i) { macc[i] = 0.f; ksum[i] = 0.f; vsum[i] = 0.f; }

  for (int tile = 0; tile < 16; ++tile) {
    const int n0 = chunk * 1024 + tile * 64;
    float kk[16], vv[16];
#pragma unroll
    for (int i = 0; i < 16; ++i) { kk[i] = kb_s[mg * 16 + i]; vv[i] = vb_s[mg * 16 + i]; }
    for (int c = 0; c < 64; ++c) {
      const float xv = x[(size_t)c * N_ + n0 + p];
#pragma unroll
      for (int i4 = 0; i4 < 4; ++i4) {
        const float4 wk = *(const float4*)&kwT[c * 68 + mg * 16 + i4 * 4];
        kk[i4 * 4 + 0] += wk.x * xv;
        kk[i4 * 4 + 1] += wk.y * xv;
        kk[i4 * 4 + 2] += wk.z * xv;
        kk[i4 * 4 + 3] += wk.w * xv;
        const float4 wvv = *(const float4*)&vwT[c * 68 + mg * 16 + i4 * 4];
        vv[i4 * 4 + 0] += wvv.x * xv;
        vv[i4 * 4 + 1] += wvv.y * xv;
        vv[i4 * 4 + 2] += wvv.z * xv;
        vv[i4 * 4 + 3] += wvv.w * xv;
      }
    }
    // L2 norm over channel dim: reduce across the 4 mg-threads of this pixel
    float ss = 0.f;
#pragma unroll
    for (int i = 0; i < 16; ++i) ss += kk[i] * kk[i];
    ss += __shfl_xor(ss, 1);
    ss += __shfl_xor(ss, 2);
    const float inv = rsqrtf(ss);
#pragma unroll
    for (int i = 0; i < 16; ++i) kk[i] *= inv;
#pragma unroll
    for (int i = 0; i < 16; ++i) { ksum[i] += kk[i]; vsum[i] += vv[i]; }

    __syncthreads();   // previous tile's matrix reads finished
#pragma unroll
    for (int i4 = 0; i4 < 4; ++i4) {
      *(float4*)&Kt[p * 68 + mg * 16 + i4 * 4] =
          make_float4(kk[i4 * 4 + 0], kk[i4 * 4 + 1], kk[i4 * 4 + 2], kk[i4 * 4 + 3]);
      *(float4*)&Vt[p * 68 + mg * 16 + i4 * 4] =
          make_float4(vv[i4 * 4 + 0], vv[i4 * 4 + 1], vv[i4 * 4 + 2], vv[i4 * 4 + 3]);
    }
    __syncthreads();
    // matrix[m][c] += K[m][pp]*V[c][pp]; each thread owns 4x4 patch
    for (int pp = 0; pp < 64; ++pp) {
      const float4 ka = *(const float4*)&Kt[pp * 68 + ty4];
      const float4 va = *(const float4*)&Vt[pp * 68 + tx4];
      macc[0]  += ka.x * va.x;  macc[1]  += ka.x * va.y;
      macc[2]  += ka.x * va.z;  macc[3]  += ka.x * va.w;
      macc[4]  += ka.y * va.x;  macc[5]  += ka.y * va.y;
      macc[6]  += ka.y * va.z;  macc[7]  += ka.y * va.w;
      macc[8]  += ka.z * va.x;  macc[9]  += ka.z * va.y;
      macc[10] += ka.z * va.z;  macc[11] += ka.z * va.w;
      macc[12] += ka.w * va.x;  macc[13] += ka.w * va.y;
      macc[14] += ka.w * va.z;  macc[15] += ka.w * va.w;
    }
  }

  float* pb = partials + ((size_t)(r * B_ + b) * CHUNKS + chunk) * STATS;
#pragma unroll
  for (int i = 0; i < 4; ++i)
#pragma unroll
    for (int j = 0; j < 4; ++j)
      pb[(ty4 + i) * 64 + tx4 + j] = macc[i * 4 + j];

  // reduce ksum/vsum over pixels via LDS reuse
  __syncthreads();
#pragma unroll
  for (int i4 = 0; i4 < 4; ++i4) {
    *(float4*)&Kt[p * 68 + mg * 16 + i4 * 4] =
        make_float4(ksum[i4 * 4 + 0], ksum[i4 * 4 + 1], ksum[i4 * 4 + 2], ksum[i4 * 4 + 3]);
    *(float4*)&Vt[p * 68 + mg * 16 + i4 * 4] =
        make_float4(vsum[i4 * 4 + 0], vsum[i4 * 4 + 1], vsum[i4 * 4 + 2], vsum[i4 * 4 + 3]);
  }
  __syncthreads();
  if (t < 64) {
    float s1 = 0.f, s2 = 0.f;
    for (int pp = 0; pp < 64; ++pp) { s1 += Kt[pp * 68 + t]; s2 += Vt[pp * 68 + t]; }
    pb[4096 + t] = s1;
    pb[4160 + t] = s2;
  }
}

// ================================================================
// Finalize: reduce partials, then fold r_w into matrix/vsum:
//   rm[o][m] = sum_c rw[o][c]*mat[m][c];  rv[o] = sum_c rw[o][c]*vsum[c]
//   kse[m] = Ksum[m] + EPS
// derived[bb] layout: [0..4095]=rm, [4096..4159]=rv, [4160..4223]=kse
// ================================================================
__global__ void finalize_kernel(const float* __restrict__ partials,
                                const float* __restrict__ r1w,
                                const float* __restrict__ r2w,
                                float* __restrict__ derived)
{
  const int bb = blockIdx.x;           // r*8 + b
  const int r = bb >> 3;
  const float* rw = r ? r2w : r1w;
  __shared__ float mat[4096];
  __shared__ float ks[64], vs[64];
  const int t = threadIdx.x;
  const float* pb = partials + (size_t)bb * CHUNKS * STATS;
  for (int e = t; e < STATS; e += 256) {
    float s = 0.f;
    for (int j = 0; j < CHUNKS; ++j) s += pb[(size_t)j * STATS + e];
    if (e < 4096) mat[e] = s;
    else if (e < 4160) ks[e - 4096] = s;
    else vs[e - 4160] = s;
  }
  __syncthreads();
  float* der = derived + (size_t)bb * STATS;
  for (int e = t; e < 4096; e += 256) {
    const int o = e >> 6, m = e & 63;
    float s = 0.f;
    for (int c = 0; c < 64; ++c) s += rw[o * 64 + c] * mat[m * 64 + c];
    der[e] = s;
  }
  if (t < 64) {
    float s = 0.f;
    for (int c = 0; c < 64; ++c) s += rw[t * 64 + c] * vs[c];
    der[4096 + t] = s;
    der[4160 + t] = ks[t] + EPSF;
  }
}

// ================================================================
// Pass 2: per-pixel Q projection + normalized-attention output,
// writes cat buffer channel block [r*64 .. r*64+64).
// ================================================================
template <typename CatT>
__global__ __launch_bounds__(256, 3) void attn_kernel(
    const float* __restrict__ t1, const float* __restrict__ t2,
    const float* __restrict__ q1w, const float* __restrict__ q1b,
    const float* __restrict__ q2w, const float* __restrict__ q2b,
    const float* __restrict__ r1b, const float* __restrict__ r2b,
    const float* __restrict__ derived,
    CatT* __restrict__ cat)
{
  const int b = blockIdx.y;
  const int r = blockIdx.z;
  const float* x  = (r ? t2 : t1) + (size_t)b * C_ * N_;
  const float* qw = r ? q2w : q1w;
  const float* qb = r ? q2b : q1b;
  const float* rb = r ? r2b : r1b;
  const float* der = derived + (size_t)(r * B_ + b) * STATS;

  __shared__ float qwT[64 * 68];
  __shared__ float rm[4096];
  __shared__ float rvs[64], kse[64], rbs[64], qbs[64];

  const int t = threadIdx.x;
  for (int idx = t; idx < 4096; idx += 256) {
    int m = idx >> 6, c = idx & 63;
    qwT[c * 68 + m] = qw[idx];
    rm[idx] = der[idx];
  }
  if (t < 64) {
    rvs[t] = der[4096 + t];
    kse[t] = der[4160 + t];
    rbs[t] = rb[t];
    qbs[t] = qb[t];
  }
  __syncthreads();

  const int n = blockIdx.x * 256 + t;
  float q[64];
#pragma unroll
  for (int m = 0; m < 64; ++m) q[m] = qbs[m];
  for (int c = 0; c < 64; ++c) {
    const float xv = x[(size_t)c * N_ + n];
#pragma unroll
    for (int m4 = 0; m4 < 16; ++m4) {
      const float4 w = *(const float4*)&qwT[c * 68 + m4 * 4];
      q[m4 * 4 + 0] += w.x * xv;
      q[m4 * 4 + 1] += w.y * xv;
      q[m4 * 4 + 2] += w.z * xv;
      q[m4 * 4 + 3] += w.w * xv;
    }
  }
  float s0 = 0.f, s1 = 0.f, s2 = 0.f, s3 = 0.f;
#pragma unroll
  for (int m = 0; m < 64; m += 4) {
    s0 += q[m] * q[m];  s1 += q[m + 1] * q[m + 1];
    s2 += q[m + 2] * q[m + 2];  s3 += q[m + 3] * q[m + 3];
  }
  const float inv = rsqrtf((s0 + s1) + (s2 + s3));
  float d0 = 0.f, d1 = 0.f, d2 = 0.f, d3 = 0.f;
#pragma unroll
  for (int m = 0; m < 64; m += 4) {
    d0 += q[m] * kse[m];  d1 += q[m + 1] * kse[m + 1];
    d2 += q[m + 2] * kse[m + 2];  d3 += q[m + 3] * kse[m + 3];
  }
  const float rden = 1.0f / (65536.0f + inv * ((d0 + d1) + (d2 + d3)));
  const float f1 = rden * inv;

  CatT* co = cat + ((size_t)b * 128 + r * 64) * N_ + n;
  for (int o = 0; o < 64; ++o) {
    float a0 = 0.f, a1 = 0.f, a2 = 0.f, a3 = 0.f;
    const float* rmo = &rm[o * 64];
#pragma unroll
    for (int m4 = 0; m4 < 16; ++m4) {
      const float4 w = *(const float4*)&rmo[m4 * 4];
      a0 += w.x * q[m4 * 4 + 0];
      a1 += w.y * q[m4 * 4 + 1];
      a2 += w.z * q[m4 * 4 + 2];
      a3 += w.w * q[m4 * 4 + 3];
    }
    const float av = f1 * ((a0 + a1) + (a2 + a3)) + rden * rvs[o] + rbs[o];
    cat_st(&co[(size_t)o * N_], av);
  }
}

// ================================================================
// Pass 3: 3x3 conv, Cin=128 -> Cout=64, SAME padding.
// Block = 16x16 output tile, 256 threads: 8 cout-groups x 32 threads,
// each thread: 8 couts x 8 pixels. Cin chunked by 16 through LDS.
// ================================================================
template <typename CatT>
__global__ __launch_bounds__(256, 2) void conv_kernel(
    const CatT* __restrict__ cat, const float* __restrict__ cw,
    const float* __restrict__ cb, float* __restrict__ out)
{
  const int bx = blockIdx.x, by = blockIdx.y, b = blockIdx.z;
  __shared__ float tile[18 * 18 * 17];   // [yy][xx][ci], ci-stride padded 17
  __shared__ float wl[64 * 16 * 9];      // [o][ci][tap]
  const int t = threadIdx.x;
  const int cog = t >> 5;          // 0..7 -> couts cog*8..+8
  const int tx32 = t & 31;
  const int pxx = tx32 & 15;
  const int py0 = tx32 >> 4;       // 0/1; thread rows = py0 + 2j

  float acc[8][8];
#pragma unroll
  for (int o = 0; o < 8; ++o) {
    const float bv = cb[cog * 8 + o];
#pragma unroll
    for (int j = 0; j < 8; ++j) acc[o][j] = bv;
  }
  const int gx0 = bx * 16, gy0 = by * 16;

  for (int chk = 0; chk < 8; ++chk) {
    const int ci0 = chk * 16;
    __syncthreads();
    for (int idx = t; idx < 18 * 18 * 16; idx += 256) {
      const int xx = idx % 18;
      const int yy = (idx / 18) % 18;
      const int ci = idx / 324;
      const int gx = gx0 + xx - 1, gy = gy0 + yy - 1;
      float v = 0.f;
      if ((unsigned)gx < 256u && (unsigned)gy < 256u)
        v = cat_ld(cat[((size_t)b * 128 + ci0 + ci) * N_ + gy * HW_ + gx]);
      tile[(yy * 18 + xx) * 17 + ci] = v;
    }
    for (int idx = t; idx < 9216; idx += 256) {
      const int tap = idx % 9;
      const int ci = (idx / 9) % 16;
      const int o = idx / 144;
      wl[idx] = cw[((size_t)o * 128 + ci0 + ci) * 9 + tap];
    }
    __syncthreads();

#pragma unroll
    for (int ky = 0; ky < 3; ++ky)
#pragma unroll
      for (int kx = 0; kx < 3; ++kx)
        for (int ci = 0; ci < 16; ++ci) {
          float w[8];
#pragma unroll
          for (int o = 0; o < 8; ++o)
            w[o] = wl[(cog * 8 + o) * 144 + ci * 9 + ky * 3 + kx];
#pragma unroll
          for (int j = 0; j < 8; ++j) {
            const float xv = tile[((py0 + 2 * j + ky) * 18 + pxx + kx) * 17 + ci];
#pragma unroll
            for (int o = 0; o < 8; ++o) acc[o][j] += w[o] * xv;
          }
        }
  }

#pragma unroll
  for (int o = 0; o < 8; ++o)
#pragma unroll
    for (int j = 0; j < 8; ++j) {
      const int gy = gy0 + py0 + 2 * j;
      const int gx = gx0 + pxx;
      out[((size_t)b * 64 + cog * 8 + o) * N_ + gy * HW_ + gx] = acc[o][j];
    }
}

// ================================================================
extern "C" void kernel_launch(void* const* d_in, const int* in_sizes, int n_in,
                              void* d_out, int out_size, void* d_ws, size_t ws_size,
                              hipStream_t stream) {
  const float* t1  = (const float*)d_in[0];
  const float* t2  = (const float*)d_in[1];
  const float* q1w = (const float*)d_in[2];
  const float* q1b = (const float*)d_in[3];
  const float* k1w = (const float*)d_in[4];
  const float* k1b = (const float*)d_in[5];
  const float* v1w = (const float*)d_in[6];
  const float* v1b = (const float*)d_in[7];
  const float* r1w = (const float*)d_in[8];
  const float* r1b = (const float*)d_in[9];
  const float* q2w = (const float*)d_in[10];
  const float* q2b = (const float*)d_in[11];
  const float* k2w = (const float*)d_in[12];
  const float* k2b = (const float*)d_in[13];
  const float* v2w = (const float*)d_in[14];
  const float* v2b = (const float*)d_in[15];
  const float* r2w = (const float*)d_in[16];
  const float* r2b = (const float*)d_in[17];
  const float* cw  = (const float*)d_in[18];
  const float* cbp = (const float*)d_in[19];
  float* out = (float*)d_out;

  char* ws = (char*)d_ws;
  const size_t catF32 = (size_t)B_ * 128 * N_ * sizeof(float);   // 256 MB
  const size_t catBF  = (size_t)B_ * 128 * N_ * 2;               // 128 MB
  const size_t partB  = (size_t)16 * CHUNKS * STATS * sizeof(float);
  const size_t derB   = (size_t)16 * STATS * sizeof(float);
  const bool useF32 = ws_size >= catF32 + partB + derB;
  const size_t catBytes = useF32 ? catF32 : catBF;
  void* catp = (void*)ws;
  float* part = (float*)(ws + catBytes);
  float* der  = (float*)(ws + catBytes + partB);

  stats_kernel<<<dim3(CHUNKS, B_, 2), 256, 0, stream>>>(
      t1, t2, k1w, k1b, v1w, v1b, k2w, k2b, v2w, v2b, part);
  finalize_kernel<<<dim3(16), 256, 0, stream>>>(part, r1w, r2w, der);
  if (useF32) {
    attn_kernel<float><<<dim3(N_ / 256, B_, 2), 256, 0, stream>>>(
        t1, t2, q1w, q1b, q2w, q2b, r1b, r2b, der, (float*)catp);
    conv_kernel<float><<<dim3(16, 16, B_), 256, 0, stream>>>(
        (const float*)catp, cw, cbp, out);
  } else {
    attn_kernel<__hip_bfloat16><<<dim3(N_ / 256, B_, 2), 256, 0, stream>>>(
        t1, t2, q1w, q1b, q2w, q2b, r1b, r2b, der, (__hip_bfloat16*)catp);
    conv_kernel<__hip_bfloat16><<<dim3(16, 16, B_), 256, 0, stream>>>(
        (const __hip_bfloat16*)catp, cw, cbp, out);
  }
}

// Round 2
// 2854.543 us; speedup vs baseline: 7.1244x; 7.1244x over previous
//
#include <hip/hip_runtime.h>
#include <hip/hip_bf16.h>

// Problem constants (fixed by setup_inputs)
constexpr int B_ = 8;
constexpr int C_ = 64;      // input channels = KC = VC = 64
constexpr int N_ = 65536;   // H*W = 256*256
constexpr int HW_ = 256;
constexpr float EPSF = 1e-6f;
constexpr int STATS = 4224; // 4096 matrix + 64 ksum + 64 vsum
constexpr int CHUNKS = 64;  // stats blocks per (branch,batch)

// ---------------- helpers for cat-buffer dtype ----------------
__device__ __forceinline__ float cat_ld(const float v) { return v; }
__device__ __forceinline__ float cat_ld(const __hip_bfloat16 v) { return __bfloat162float(v); }
__device__ __forceinline__ void cat_st(float* p, float v) { *p = v; }
__device__ __forceinline__ void cat_st(__hip_bfloat16* p, float v) { *p = __float2bfloat16(v); }

// ================================================================
// Pass 1: per (branch,batch,chunk) compute partial Ksum/Vsum/matrix.
// (unchanged from round 1 — conv dominated; isolate the conv fix)
// ================================================================
__global__ __launch_bounds__(256, 2) void stats_kernel(
    const float* __restrict__ t1, const float* __restrict__ t2,
    const float* __restrict__ k1w, const float* __restrict__ k1b,
    const float* __restrict__ v1w, const float* __restrict__ v1b,
    const float* __restrict__ k2w, const float* __restrict__ k2b,
    const float* __restrict__ v2w, const float* __restrict__ v2b,
    float* __restrict__ partials)   // [2*B][CHUNKS][STATS]
{
  const int chunk = blockIdx.x;
  const int b = blockIdx.y;
  const int r = blockIdx.z;
  const float* x  = (r ? t2 : t1) + (size_t)b * C_ * N_;
  const float* kw = r ? k2w : k1w;
  const float* kb = r ? k2b : k1b;
  const float* vw = r ? v2w : v1w;
  const float* vb = r ? v2b : v1b;

  __shared__ float kwT[64 * 68];
  __shared__ float vwT[64 * 68];
  __shared__ float Kt[64 * 68];
  __shared__ float Vt[64 * 68];
  __shared__ float kb_s[64], vb_s[64];

  const int t = threadIdx.x;
  for (int idx = t; idx < 4096; idx += 256) {
    int m = idx >> 6, c = idx & 63;
    kwT[c * 68 + m] = kw[idx];
    vwT[c * 68 + m] = vw[idx];
  }
  if (t < 64) { kb_s[t] = kb[t]; vb_s[t] = vb[t]; }
  __syncthreads();

  const int mg = t & 3;       // channel group: channels mg*16 .. +16
  const int p  = t >> 2;      // pixel within tile (0..63)
  const int ty4 = (t >> 4) * 4;  // matrix-stage row base
  const int tx4 = (t & 15) * 4;  // matrix-stage col base

  float macc[16];
  float ksum[16], vsum[16];
#pragma unroll
  for (int i = 0; i < 16; ++i) { macc[i] = 0.f; ksum[i] = 0.f; vsum[i] = 0.f; }

  for (int tile = 0; tile < 16; ++tile) {
    const int n0 = chunk * 1024 + tile * 64;
    float kk[16], vv[16];
#pragma unroll
    for (int i = 0; i < 16; ++i) { kk[i] = kb_s[mg * 16 + i]; vv[i] = vb_s[mg * 16 + i]; }
    for (int c = 0; c < 64; ++c) {
      const float xv = x[(size_t)c * N_ + n0 + p];
#pragma unroll
      for (int i4 = 0; i4 < 4; ++i4) {
        const float4 wk = *(const float4*)&kwT[c * 68 + mg * 16 + i4 * 4];
        kk[i4 * 4 + 0] += wk.x * xv;
        kk[i4 * 4 + 1] += wk.y * xv;
        kk[i4 * 4 + 2] += wk.z * xv;
        kk[i4 * 4 + 3] += wk.w * xv;
        const float4 wvv = *(const float4*)&vwT[c * 68 + mg * 16 + i4 * 4];
        vv[i4 * 4 + 0] += wvv.x * xv;
        vv[i4 * 4 + 1] += wvv.y * xv;
        vv[i4 * 4 + 2] += wvv.z * xv;
        vv[i4 * 4 + 3] += wvv.w * xv;
      }
    }
    // L2 norm over channel dim: reduce across the 4 mg-threads of this pixel
    float ss = 0.f;
#pragma unroll
    for (int i = 0; i < 16; ++i) ss += kk[i] * kk[i];
    ss += __shfl_xor(ss, 1);
    ss += __shfl_xor(ss, 2);
    const float inv = rsqrtf(ss);
#pragma unroll
    for (int i = 0; i < 16; ++i) kk[i] *= inv;
#pragma unroll
    for (int i = 0; i < 16; ++i) { ksum[i] += kk[i]; vsum[i] += vv[i]; }

    __syncthreads();   // previous tile's matrix reads finished
#pragma unroll
    for (int i4 = 0; i4 < 4; ++i4) {
      *(float4*)&Kt[p * 68 + mg * 16 + i4 * 4] =
          make_float4(kk[i4 * 4 + 0], kk[i4 * 4 + 1], kk[i4 * 4 + 2], kk[i4 * 4 + 3]);
      *(float4*)&Vt[p * 68 + mg * 16 + i4 * 4] =
          make_float4(vv[i4 * 4 + 0], vv[i4 * 4 + 1], vv[i4 * 4 + 2], vv[i4 * 4 + 3]);
    }
    __syncthreads();
    // matrix[m][c] += K[m][pp]*V[c][pp]; each thread owns 4x4 patch
    for (int pp = 0; pp < 64; ++pp) {
      const float4 ka = *(const float4*)&Kt[pp * 68 + ty4];
      const float4 va = *(const float4*)&Vt[pp * 68 + tx4];
      macc[0]  += ka.x * va.x;  macc[1]  += ka.x * va.y;
      macc[2]  += ka.x * va.z;  macc[3]  += ka.x * va.w;
      macc[4]  += ka.y * va.x;  macc[5]  += ka.y * va.y;
      macc[6]  += ka.y * va.z;  macc[7]  += ka.y * va.w;
      macc[8]  += ka.z * va.x;  macc[9]  += ka.z * va.y;
      macc[10] += ka.z * va.z;  macc[11] += ka.z * va.w;
      macc[12] += ka.w * va.x;  macc[13] += ka.w * va.y;
      macc[14] += ka.w * va.z;  macc[15] += ka.w * va.w;
    }
  }

  float* pb = partials + ((size_t)(r * B_ + b) * CHUNKS + chunk) * STATS;
#pragma unroll
  for (int i = 0; i < 4; ++i)
#pragma unroll
    for (int j = 0; j < 4; ++j)
      pb[(ty4 + i) * 64 + tx4 + j] = macc[i * 4 + j];

  // reduce ksum/vsum over pixels via LDS reuse
  __syncthreads();
#pragma unroll
  for (int i4 = 0; i4 < 4; ++i4) {
    *(float4*)&Kt[p * 68 + mg * 16 + i4 * 4] =
        make_float4(ksum[i4 * 4 + 0], ksum[i4 * 4 + 1], ksum[i4 * 4 + 2], ksum[i4 * 4 + 3]);
    *(float4*)&Vt[p * 68 + mg * 16 + i4 * 4] =
        make_float4(vsum[i4 * 4 + 0], vsum[i4 * 4 + 1], vsum[i4 * 4 + 2], vsum[i4 * 4 + 3]);
  }
  __syncthreads();
  if (t < 64) {
    float s1 = 0.f, s2 = 0.f;
    for (int pp = 0; pp < 64; ++pp) { s1 += Kt[pp * 68 + t]; s2 += Vt[pp * 68 + t]; }
    pb[4096 + t] = s1;
    pb[4160 + t] = s2;
  }
}

// ================================================================
// Finalize: reduce partials, fold r_w in. (unchanged)
// ================================================================
__global__ void finalize_kernel(const float* __restrict__ partials,
                                const float* __restrict__ r1w,
                                const float* __restrict__ r2w,
                                float* __restrict__ derived)
{
  const int bb = blockIdx.x;           // r*8 + b
  const int r = bb >> 3;
  const float* rw = r ? r2w : r1w;
  __shared__ float mat[4096];
  __shared__ float ks[64], vs[64];
  const int t = threadIdx.x;
  const float* pb = partials + (size_t)bb * CHUNKS * STATS;
  for (int e = t; e < STATS; e += 256) {
    float s = 0.f;
    for (int j = 0; j < CHUNKS; ++j) s += pb[(size_t)j * STATS + e];
    if (e < 4096) mat[e] = s;
    else if (e < 4160) ks[e - 4096] = s;
    else vs[e - 4160] = s;
  }
  __syncthreads();
  float* der = derived + (size_t)bb * STATS;
  for (int e = t; e < 4096; e += 256) {
    const int o = e >> 6, m = e & 63;
    float s = 0.f;
    for (int c = 0; c < 64; ++c) s += rw[o * 64 + c] * mat[m * 64 + c];
    der[e] = s;
  }
  if (t < 64) {
    float s = 0.f;
    for (int c = 0; c < 64; ++c) s += rw[t * 64 + c] * vs[c];
    der[4096 + t] = s;
    der[4160 + t] = ks[t] + EPSF;
  }
}

// ================================================================
// Pass 2: per-pixel Q projection + attention output. (unchanged)
// ================================================================
template <typename CatT>
__global__ __launch_bounds__(256, 3) void attn_kernel(
    const float* __restrict__ t1, const float* __restrict__ t2,
    const float* __restrict__ q1w, const float* __restrict__ q1b,
    const float* __restrict__ q2w, const float* __restrict__ q2b,
    const float* __restrict__ r1b, const float* __restrict__ r2b,
    const float* __restrict__ derived,
    CatT* __restrict__ cat)
{
  const int b = blockIdx.y;
  const int r = blockIdx.z;
  const float* x  = (r ? t2 : t1) + (size_t)b * C_ * N_;
  const float* qw = r ? q2w : q1w;
  const float* qb = r ? q2b : q1b;
  const float* rb = r ? r2b : r1b;
  const float* der = derived + (size_t)(r * B_ + b) * STATS;

  __shared__ float qwT[64 * 68];
  __shared__ float rm[4096];
  __shared__ float rvs[64], kse[64], rbs[64], qbs[64];

  const int t = threadIdx.x;
  for (int idx = t; idx < 4096; idx += 256) {
    int m = idx >> 6, c = idx & 63;
    qwT[c * 68 + m] = qw[idx];
    rm[idx] = der[idx];
  }
  if (t < 64) {
    rvs[t] = der[4096 + t];
    kse[t] = der[4160 + t];
    rbs[t] = rb[t];
    qbs[t] = qb[t];
  }
  __syncthreads();

  const int n = blockIdx.x * 256 + t;
  float q[64];
#pragma unroll
  for (int m = 0; m < 64; ++m) q[m] = qbs[m];
  for (int c = 0; c < 64; ++c) {
    const float xv = x[(size_t)c * N_ + n];
#pragma unroll
    for (int m4 = 0; m4 < 16; ++m4) {
      const float4 w = *(const float4*)&qwT[c * 68 + m4 * 4];
      q[m4 * 4 + 0] += w.x * xv;
      q[m4 * 4 + 1] += w.y * xv;
      q[m4 * 4 + 2] += w.z * xv;
      q[m4 * 4 + 3] += w.w * xv;
    }
  }
  float s0 = 0.f, s1 = 0.f, s2 = 0.f, s3 = 0.f;
#pragma unroll
  for (int m = 0; m < 64; m += 4) {
    s0 += q[m] * q[m];  s1 += q[m + 1] * q[m + 1];
    s2 += q[m + 2] * q[m + 2];  s3 += q[m + 3] * q[m + 3];
  }
  const float inv = rsqrtf((s0 + s1) + (s2 + s3));
  float d0 = 0.f, d1 = 0.f, d2 = 0.f, d3 = 0.f;
#pragma unroll
  for (int m = 0; m < 64; m += 4) {
    d0 += q[m] * kse[m];  d1 += q[m + 1] * kse[m + 1];
    d2 += q[m + 2] * kse[m + 2];  d3 += q[m + 3] * kse[m + 3];
  }
  const float rden = 1.0f / (65536.0f + inv * ((d0 + d1) + (d2 + d3)));
  const float f1 = rden * inv;

  CatT* co = cat + ((size_t)b * 128 + r * 64) * N_ + n;
  for (int o = 0; o < 64; ++o) {
    float a0 = 0.f, a1 = 0.f, a2 = 0.f, a3 = 0.f;
    const float* rmo = &rm[o * 64];
#pragma unroll
    for (int m4 = 0; m4 < 16; ++m4) {
      const float4 w = *(const float4*)&rmo[m4 * 4];
      a0 += w.x * q[m4 * 4 + 0];
      a1 += w.y * q[m4 * 4 + 1];
      a2 += w.z * q[m4 * 4 + 2];
      a3 += w.w * q[m4 * 4 + 3];
    }
    const float av = f1 * ((a0 + a1) + (a2 + a3)) + rden * rvs[o] + rbs[o];
    cat_st(&co[(size_t)o * N_], av);
  }
}

// ================================================================
// Weight pre-transpose: cw [O=64][I=128][9] -> cwT [I=128][9][O=64]
// so per-block weight staging is a contiguous coalesced copy.
// ================================================================
__global__ void transpose_cw_kernel(const float* __restrict__ cw,
                                    float* __restrict__ cwT) {
  const int e = blockIdx.x * 256 + threadIdx.x;   // over 128*9*64 = 73728
  if (e < 73728) {
    const int o = e & 63;
    const int tap = (e >> 6) % 9;
    const int ci = e / 576;
    cwT[e] = cw[(size_t)o * 1152 + ci * 9 + tap];
  }
}

// ================================================================
// Pass 3 (REWRITTEN): 3x3 conv, Cin=128 -> Cout=64, SAME padding.
// Block = 512 threads: col c = t&63, cout-group cog = t>>6 (8 couts).
// Block output tile: 4 rows x 64 cols x 64 couts -> 32 acc/thread,
// flat + statically indexed (no spill). ci chunked by 8 through LDS.
// LDS 32 KB -> 2 blocks/CU at VGPR<=128 (__launch_bounds__(512,4)).
// Weight reads are wave-uniform float4 broadcasts; tile reads stride-1.
// ================================================================
template <typename CatT>
__global__ __launch_bounds__(512, 4) void conv_kernel(
    const CatT* __restrict__ cat, const float* __restrict__ cwT,
    const float* __restrict__ cb, float* __restrict__ out)
{
  __shared__ float tile[8 * 6 * 72];   // [ci][row][col], 13.8 KB
  __shared__ float wl[8 * 9 * 64];     // [ci][tap][o],   18.4 KB

  const int t = threadIdx.x;
  const int c = t & 63;          // output column within tile
  const int cog = t >> 6;        // 0..7 -> couts cog*8..+8 ; also wave id
  const int lane = t & 63;
  const int gx0 = blockIdx.x * 64;
  const int gy0 = blockIdx.y * 4;
  const int b = blockIdx.z;

  float acc[32];                 // acc[o*4 + j], o=0..7 couts, j=0..3 rows
#pragma unroll
  for (int i = 0; i < 32; ++i) acc[i] = 0.f;

  for (int chk = 0; chk < 16; ++chk) {
    const int ci0 = chk * 8;
    __syncthreads();             // previous chunk's compute reads done

    // ---- stage input tile: wave 'cog' owns channel ci=cog ----
    {
      const int ci = cog;
      const CatT* src = cat + ((size_t)b * 128 + ci0 + ci) * (size_t)N_;
#pragma unroll
      for (int row = 0; row < 6; ++row) {
        const int gy = gy0 + row - 1;
        const bool yok = (unsigned)gy < 256u;
        const CatT* srow = src + (size_t)gy * HW_ + gx0 - 1;
        float* dst = &tile[(ci * 6 + row) * 72];
        const int gx = gx0 - 1 + lane;
        float v = 0.f;
        if (yok && (unsigned)gx < 256u) v = cat_ld(srow[lane]);
        dst[lane] = v;
        if (lane < 2) {
          const int gx2 = gx0 + 63 + lane;
          float v2 = 0.f;
          if (yok && (unsigned)gx2 < 256u) v2 = cat_ld(srow[64 + lane]);
          dst[64 + lane] = v2;
        }
      }
    }
    // ---- stage weights: contiguous coalesced copy from cwT ----
    for (int idx = t; idx < 4608; idx += 512)
      wl[idx] = cwT[(size_t)ci0 * 576 + idx];
    __syncthreads();

    // ---- compute ----
#pragma unroll 2
    for (int ci = 0; ci < 8; ++ci) {
      float xr[18];              // xr[row*3 + d], rows 0..5 of tile, cols c..c+2
#pragma unroll
      for (int row = 0; row < 6; ++row)
#pragma unroll
        for (int d = 0; d < 3; ++d)
          xr[row * 3 + d] = tile[(ci * 6 + row) * 72 + c + d];
#pragma unroll
      for (int ky = 0; ky < 3; ++ky)
#pragma unroll
        for (int kx = 0; kx < 3; ++kx) {
          const float* wp = &wl[(ci * 9 + ky * 3 + kx) * 64 + cog * 8];
          const float4 w0 = *(const float4*)wp;        // wave-uniform -> broadcast
          const float4 w1 = *(const float4*)(wp + 4);
#pragma unroll
          for (int j = 0; j < 4; ++j) {
            const float xv = xr[(j + ky) * 3 + kx];
            acc[0  + j] += w0.x * xv;  acc[4  + j] += w0.y * xv;
            acc[8  + j] += w0.z * xv;  acc[12 + j] += w0.w * xv;
            acc[16 + j] += w1.x * xv;  acc[20 + j] += w1.y * xv;
            acc[24 + j] += w1.z * xv;  acc[28 + j] += w1.w * xv;
          }
        }
    }
  }

#pragma unroll
  for (int o = 0; o < 8; ++o) {
    const float bv = cb[cog * 8 + o];
#pragma unroll
    for (int j = 0; j < 4; ++j) {
      out[((size_t)b * 64 + cog * 8 + o) * N_ + (size_t)(gy0 + j) * HW_ + gx0 + c]
          = acc[o * 4 + j] + bv;
    }
  }
}

// ================================================================
extern "C" void kernel_launch(void* const* d_in, const int* in_sizes, int n_in,
                              void* d_out, int out_size, void* d_ws, size_t ws_size,
                              hipStream_t stream) {
  const float* t1  = (const float*)d_in[0];
  const float* t2  = (const float*)d_in[1];
  const float* q1w = (const float*)d_in[2];
  const float* q1b = (const float*)d_in[3];
  const float* k1w = (const float*)d_in[4];
  const float* k1b = (const float*)d_in[5];
  const float* v1w = (const float*)d_in[6];
  const float* v1b = (const float*)d_in[7];
  const float* r1w = (const float*)d_in[8];
  const float* r1b = (const float*)d_in[9];
  const float* q2w = (const float*)d_in[10];
  const float* q2b = (const float*)d_in[11];
  const float* k2w = (const float*)d_in[12];
  const float* k2b = (const float*)d_in[13];
  const float* v2w = (const float*)d_in[14];
  const float* v2b = (const float*)d_in[15];
  const float* r2w = (const float*)d_in[16];
  const float* r2b = (const float*)d_in[17];
  const float* cw  = (const float*)d_in[18];
  const float* cbp = (const float*)d_in[19];
  float* out = (float*)d_out;

  char* ws = (char*)d_ws;
  const size_t catF32 = (size_t)B_ * 128 * N_ * sizeof(float);   // 256 MB
  const size_t catBF  = (size_t)B_ * 128 * N_ * 2;               // 128 MB
  const size_t partB  = (size_t)16 * CHUNKS * STATS * sizeof(float);
  const size_t derB   = (size_t)16 * STATS * sizeof(float);
  const size_t cwB    = (size_t)73728 * sizeof(float);
  const bool useF32 = ws_size >= catF32 + partB + derB + cwB;
  const size_t catBytes = useF32 ? catF32 : catBF;
  void* catp = (void*)ws;
  float* part = (float*)(ws + catBytes);
  float* der  = (float*)(ws + catBytes + partB);
  float* cwT  = (float*)(ws + catBytes + partB + derB);

  transpose_cw_kernel<<<dim3(288), 256, 0, stream>>>(cw, cwT);
  stats_kernel<<<dim3(CHUNKS, B_, 2), 256, 0, stream>>>(
      t1, t2, k1w, k1b, v1w, v1b, k2w, k2b, v2w, v2b, part);
  finalize_kernel<<<dim3(16), 256, 0, stream>>>(part, r1w, r2w, der);
  if (useF32) {
    attn_kernel<float><<<dim3(N_ / 256, B_, 2), 256, 0, stream>>>(
        t1, t2, q1w, q1b, q2w, q2b, r1b, r2b, der, (float*)catp);
    conv_kernel<float><<<dim3(4, 64, B_), 512, 0, stream>>>(
        (const float*)catp, cwT, cbp, out);
  } else {
    attn_kernel<__hip_bfloat16><<<dim3(N_ / 256, B_, 2), 256, 0, stream>>>(
        t1, t2, q1w, q1b, q2w, q2b, r1b, r2b, der, (__hip_bfloat16*)catp);
    conv_kernel<__hip_bfloat16><<<dim3(4, 64, B_), 512, 0, stream>>>(
        (const __hip_bfloat16*)catp, cwT, cbp, out);
  }
}

// Round 3
// 2795.494 us; speedup vs baseline: 7.2748x; 1.0211x over previous
//
#include <hip/hip_runtime.h>
#include <hip/hip_bf16.h>

// Problem constants (fixed by setup_inputs)
constexpr int B_ = 8;
constexpr int C_ = 64;      // input channels = KC = VC = 64
constexpr int N_ = 65536;   // H*W = 256*256
constexpr int HW_ = 256;
constexpr float EPSF = 1e-6f;
constexpr int STATS = 4224; // 4096 matrix + 64 ksum + 64 vsum
constexpr int CHUNKS = 64;  // stats blocks per (branch,batch)

// ---------------- helpers for cat-buffer dtype ----------------
__device__ __forceinline__ float cat_ld(const float v) { return v; }
__device__ __forceinline__ float cat_ld(const __hip_bfloat16 v) { return __bfloat162float(v); }
__device__ __forceinline__ void cat_st(float* p, float v) { *p = v; }
__device__ __forceinline__ void cat_st(__hip_bfloat16* p, float v) { *p = __float2bfloat16(v); }

// ================================================================
// Pass 1: per (branch,batch,chunk) compute partial Ksum/Vsum/matrix.
// (unchanged — isolate the conv launch-bounds fix)
// ================================================================
__global__ __launch_bounds__(256, 2) void stats_kernel(
    const float* __restrict__ t1, const float* __restrict__ t2,
    const float* __restrict__ k1w, const float* __restrict__ k1b,
    const float* __restrict__ v1w, const float* __restrict__ v1b,
    const float* __restrict__ k2w, const float* __restrict__ k2b,
    const float* __restrict__ v2w, const float* __restrict__ v2b,
    float* __restrict__ partials)   // [2*B][CHUNKS][STATS]
{
  const int chunk = blockIdx.x;
  const int b = blockIdx.y;
  const int r = blockIdx.z;
  const float* x  = (r ? t2 : t1) + (size_t)b * C_ * N_;
  const float* kw = r ? k2w : k1w;
  const float* kb = r ? k2b : k1b;
  const float* vw = r ? v2w : v1w;
  const float* vb = r ? v2b : v1b;

  __shared__ float kwT[64 * 68];
  __shared__ float vwT[64 * 68];
  __shared__ float Kt[64 * 68];
  __shared__ float Vt[64 * 68];
  __shared__ float kb_s[64], vb_s[64];

  const int t = threadIdx.x;
  for (int idx = t; idx < 4096; idx += 256) {
    int m = idx >> 6, c = idx & 63;
    kwT[c * 68 + m] = kw[idx];
    vwT[c * 68 + m] = vw[idx];
  }
  if (t < 64) { kb_s[t] = kb[t]; vb_s[t] = vb[t]; }
  __syncthreads();

  const int mg = t & 3;       // channel group: channels mg*16 .. +16
  const int p  = t >> 2;      // pixel within tile (0..63)
  const int ty4 = (t >> 4) * 4;  // matrix-stage row base
  const int tx4 = (t & 15) * 4;  // matrix-stage col base

  float macc[16];
  float ksum[16], vsum[16];
#pragma unroll
  for (int i = 0; i < 16; ++i) { macc[i] = 0.f; ksum[i] = 0.f; vsum[i] = 0.f; }

  for (int tile = 0; tile < 16; ++tile) {
    const int n0 = chunk * 1024 + tile * 64;
    float kk[16], vv[16];
#pragma unroll
    for (int i = 0; i < 16; ++i) { kk[i] = kb_s[mg * 16 + i]; vv[i] = vb_s[mg * 16 + i]; }
    for (int c = 0; c < 64; ++c) {
      const float xv = x[(size_t)c * N_ + n0 + p];
#pragma unroll
      for (int i4 = 0; i4 < 4; ++i4) {
        const float4 wk = *(const float4*)&kwT[c * 68 + mg * 16 + i4 * 4];
        kk[i4 * 4 + 0] += wk.x * xv;
        kk[i4 * 4 + 1] += wk.y * xv;
        kk[i4 * 4 + 2] += wk.z * xv;
        kk[i4 * 4 + 3] += wk.w * xv;
        const float4 wvv = *(const float4*)&vwT[c * 68 + mg * 16 + i4 * 4];
        vv[i4 * 4 + 0] += wvv.x * xv;
        vv[i4 * 4 + 1] += wvv.y * xv;
        vv[i4 * 4 + 2] += wvv.z * xv;
        vv[i4 * 4 + 3] += wvv.w * xv;
      }
    }
    // L2 norm over channel dim: reduce across the 4 mg-threads of this pixel
    float ss = 0.f;
#pragma unroll
    for (int i = 0; i < 16; ++i) ss += kk[i] * kk[i];
    ss += __shfl_xor(ss, 1);
    ss += __shfl_xor(ss, 2);
    const float inv = rsqrtf(ss);
#pragma unroll
    for (int i = 0; i < 16; ++i) kk[i] *= inv;
#pragma unroll
    for (int i = 0; i < 16; ++i) { ksum[i] += kk[i]; vsum[i] += vv[i]; }

    __syncthreads();   // previous tile's matrix reads finished
#pragma unroll
    for (int i4 = 0; i4 < 4; ++i4) {
      *(float4*)&Kt[p * 68 + mg * 16 + i4 * 4] =
          make_float4(kk[i4 * 4 + 0], kk[i4 * 4 + 1], kk[i4 * 4 + 2], kk[i4 * 4 + 3]);
      *(float4*)&Vt[p * 68 + mg * 16 + i4 * 4] =
          make_float4(vv[i4 * 4 + 0], vv[i4 * 4 + 1], vv[i4 * 4 + 2], vv[i4 * 4 + 3]);
    }
    __syncthreads();
    // matrix[m][c] += K[m][pp]*V[c][pp]; each thread owns 4x4 patch
    for (int pp = 0; pp < 64; ++pp) {
      const float4 ka = *(const float4*)&Kt[pp * 68 + ty4];
      const float4 va = *(const float4*)&Vt[pp * 68 + tx4];
      macc[0]  += ka.x * va.x;  macc[1]  += ka.x * va.y;
      macc[2]  += ka.x * va.z;  macc[3]  += ka.x * va.w;
      macc[4]  += ka.y * va.x;  macc[5]  += ka.y * va.y;
      macc[6]  += ka.y * va.z;  macc[7]  += ka.y * va.w;
      macc[8]  += ka.z * va.x;  macc[9]  += ka.z * va.y;
      macc[10] += ka.z * va.z;  macc[11] += ka.z * va.w;
      macc[12] += ka.w * va.x;  macc[13] += ka.w * va.y;
      macc[14] += ka.w * va.z;  macc[15] += ka.w * va.w;
    }
  }

  float* pb = partials + ((size_t)(r * B_ + b) * CHUNKS + chunk) * STATS;
#pragma unroll
  for (int i = 0; i < 4; ++i)
#pragma unroll
    for (int j = 0; j < 4; ++j)
      pb[(ty4 + i) * 64 + tx4 + j] = macc[i * 4 + j];

  // reduce ksum/vsum over pixels via LDS reuse
  __syncthreads();
#pragma unroll
  for (int i4 = 0; i4 < 4; ++i4) {
    *(float4*)&Kt[p * 68 + mg * 16 + i4 * 4] =
        make_float4(ksum[i4 * 4 + 0], ksum[i4 * 4 + 1], ksum[i4 * 4 + 2], ksum[i4 * 4 + 3]);
    *(float4*)&Vt[p * 68 + mg * 16 + i4 * 4] =
        make_float4(vsum[i4 * 4 + 0], vsum[i4 * 4 + 1], vsum[i4 * 4 + 2], vsum[i4 * 4 + 3]);
  }
  __syncthreads();
  if (t < 64) {
    float s1 = 0.f, s2 = 0.f;
    for (int pp = 0; pp < 64; ++pp) { s1 += Kt[pp * 68 + t]; s2 += Vt[pp * 68 + t]; }
    pb[4096 + t] = s1;
    pb[4160 + t] = s2;
  }
}

// ================================================================
// Finalize: reduce partials, fold r_w in. (unchanged)
// ================================================================
__global__ void finalize_kernel(const float* __restrict__ partials,
                                const float* __restrict__ r1w,
                                const float* __restrict__ r2w,
                                float* __restrict__ derived)
{
  const int bb = blockIdx.x;           // r*8 + b
  const int r = bb >> 3;
  const float* rw = r ? r2w : r1w;
  __shared__ float mat[4096];
  __shared__ float ks[64], vs[64];
  const int t = threadIdx.x;
  const float* pb = partials + (size_t)bb * CHUNKS * STATS;
  for (int e = t; e < STATS; e += 256) {
    float s = 0.f;
    for (int j = 0; j < CHUNKS; ++j) s += pb[(size_t)j * STATS + e];
    if (e < 4096) mat[e] = s;
    else if (e < 4160) ks[e - 4096] = s;
    else vs[e - 4160] = s;
  }
  __syncthreads();
  float* der = derived + (size_t)bb * STATS;
  for (int e = t; e < 4096; e += 256) {
    const int o = e >> 6, m = e & 63;
    float s = 0.f;
    for (int c = 0; c < 64; ++c) s += rw[o * 64 + c] * mat[m * 64 + c];
    der[e] = s;
  }
  if (t < 64) {
    float s = 0.f;
    for (int c = 0; c < 64; ++c) s += rw[t * 64 + c] * vs[c];
    der[4096 + t] = s;
    der[4160 + t] = ks[t] + EPSF;
  }
}

// ================================================================
// Pass 2: per-pixel Q projection + attention output. (unchanged)
// ================================================================
template <typename CatT>
__global__ __launch_bounds__(256, 3) void attn_kernel(
    const float* __restrict__ t1, const float* __restrict__ t2,
    const float* __restrict__ q1w, const float* __restrict__ q1b,
    const float* __restrict__ q2w, const float* __restrict__ q2b,
    const float* __restrict__ r1b, const float* __restrict__ r2b,
    const float* __restrict__ derived,
    CatT* __restrict__ cat)
{
  const int b = blockIdx.y;
  const int r = blockIdx.z;
  const float* x  = (r ? t2 : t1) + (size_t)b * C_ * N_;
  const float* qw = r ? q2w : q1w;
  const float* qb = r ? q2b : q1b;
  const float* rb = r ? r2b : r1b;
  const float* der = derived + (size_t)(r * B_ + b) * STATS;

  __shared__ float qwT[64 * 68];
  __shared__ float rm[4096];
  __shared__ float rvs[64], kse[64], rbs[64], qbs[64];

  const int t = threadIdx.x;
  for (int idx = t; idx < 4096; idx += 256) {
    int m = idx >> 6, c = idx & 63;
    qwT[c * 68 + m] = qw[idx];
    rm[idx] = der[idx];
  }
  if (t < 64) {
    rvs[t] = der[4096 + t];
    kse[t] = der[4160 + t];
    rbs[t] = rb[t];
    qbs[t] = qb[t];
  }
  __syncthreads();

  const int n = blockIdx.x * 256 + t;
  float q[64];
#pragma unroll
  for (int m = 0; m < 64; ++m) q[m] = qbs[m];
  for (int c = 0; c < 64; ++c) {
    const float xv = x[(size_t)c * N_ + n];
#pragma unroll
    for (int m4 = 0; m4 < 16; ++m4) {
      const float4 w = *(const float4*)&qwT[c * 68 + m4 * 4];
      q[m4 * 4 + 0] += w.x * xv;
      q[m4 * 4 + 1] += w.y * xv;
      q[m4 * 4 + 2] += w.z * xv;
      q[m4 * 4 + 3] += w.w * xv;
    }
  }
  float s0 = 0.f, s1 = 0.f, s2 = 0.f, s3 = 0.f;
#pragma unroll
  for (int m = 0; m < 64; m += 4) {
    s0 += q[m] * q[m];  s1 += q[m + 1] * q[m + 1];
    s2 += q[m + 2] * q[m + 2];  s3 += q[m + 3] * q[m + 3];
  }
  const float inv = rsqrtf((s0 + s1) + (s2 + s3));
  float d0 = 0.f, d1 = 0.f, d2 = 0.f, d3 = 0.f;
#pragma unroll
  for (int m = 0; m < 64; m += 4) {
    d0 += q[m] * kse[m];  d1 += q[m + 1] * kse[m + 1];
    d2 += q[m + 2] * kse[m + 2];  d3 += q[m + 3] * kse[m + 3];
  }
  const float rden = 1.0f / (65536.0f + inv * ((d0 + d1) + (d2 + d3)));
  const float f1 = rden * inv;

  CatT* co = cat + ((size_t)b * 128 + r * 64) * N_ + n;
  for (int o = 0; o < 64; ++o) {
    float a0 = 0.f, a1 = 0.f, a2 = 0.f, a3 = 0.f;
    const float* rmo = &rm[o * 64];
#pragma unroll
    for (int m4 = 0; m4 < 16; ++m4) {
      const float4 w = *(const float4*)&rmo[m4 * 4];
      a0 += w.x * q[m4 * 4 + 0];
      a1 += w.y * q[m4 * 4 + 1];
      a2 += w.z * q[m4 * 4 + 2];
      a3 += w.w * q[m4 * 4 + 3];
    }
    const float av = f1 * ((a0 + a1) + (a2 + a3)) + rden * rvs[o] + rbs[o];
    cat_st(&co[(size_t)o * N_], av);
  }
}

// ================================================================
// Weight pre-transpose: cw [O=64][I=128][9] -> cwT [I=128][9][O=64]
// ================================================================
__global__ void transpose_cw_kernel(const float* __restrict__ cw,
                                    float* __restrict__ cwT) {
  const int e = blockIdx.x * 256 + threadIdx.x;   // over 128*9*64 = 73728
  if (e < 73728) {
    const int o = e & 63;
    const int tap = (e >> 6) % 9;
    const int ci = e / 576;
    cwT[e] = cw[(size_t)o * 1152 + ci * 9 + tap];
  }
}

// ================================================================
// Pass 3: 3x3 conv, Cin=128 -> Cout=64, SAME padding.
// Block = 512 threads: col c = t&63, cout-group cog = t>>6 (8 couts).
// Block output tile: 4 rows x 64 cols x 64 couts -> 32 acc/thread.
// ROUND-3 FIX: __launch_bounds__(512, 2) — round 2's (512,4) budgeted
// 8 waves/SIMD -> 64-VGPR cap -> acc[]/xr[] spilled to scratch
// (2.5 GB phantom writes, 18x output size). Cap 256 VGPR; body needs
// ~80-110 -> no spill, ~5 waves/SIMD occupancy, VALU-bound.
// ================================================================
template <typename CatT>
__global__ __launch_bounds__(512, 2) void conv_kernel(
    const CatT* __restrict__ cat, const float* __restrict__ cwT,
    const float* __restrict__ cb, float* __restrict__ out)
{
  __shared__ float tile[8 * 6 * 72];   // [ci][row][col], 13.8 KB
  __shared__ float wl[8 * 9 * 64];     // [ci][tap][o],   18.4 KB

  const int t = threadIdx.x;
  const int c = t & 63;          // output column within tile
  const int cog = t >> 6;        // 0..7 -> couts cog*8..+8 ; also wave id
  const int lane = t & 63;
  const int gx0 = blockIdx.x * 64;
  const int gy0 = blockIdx.y * 4;
  const int b = blockIdx.z;

  float acc[32];                 // acc[o*4 + j], o=0..7 couts, j=0..3 rows
#pragma unroll
  for (int i = 0; i < 32; ++i) acc[i] = 0.f;

  for (int chk = 0; chk < 16; ++chk) {
    const int ci0 = chk * 8;
    __syncthreads();             // previous chunk's compute reads done

    // ---- stage input tile: wave 'cog' owns channel ci=cog ----
    {
      const int ci = cog;
      const CatT* src = cat + ((size_t)b * 128 + ci0 + ci) * (size_t)N_;
#pragma unroll
      for (int row = 0; row < 6; ++row) {
        const int gy = gy0 + row - 1;
        const bool yok = (unsigned)gy < 256u;
        const CatT* srow = src + (size_t)gy * HW_ + gx0 - 1;
        float* dst = &tile[(ci * 6 + row) * 72];
        const int gx = gx0 - 1 + lane;
        float v = 0.f;
        if (yok && (unsigned)gx < 256u) v = cat_ld(srow[lane]);
        dst[lane] = v;
        if (lane < 2) {
          const int gx2 = gx0 + 63 + lane;
          float v2 = 0.f;
          if (yok && (unsigned)gx2 < 256u) v2 = cat_ld(srow[64 + lane]);
          dst[64 + lane] = v2;
        }
      }
    }
    // ---- stage weights: contiguous coalesced copy from cwT ----
    for (int idx = t; idx < 4608; idx += 512)
      wl[idx] = cwT[(size_t)ci0 * 576 + idx];
    __syncthreads();

    // ---- compute ----
#pragma unroll 2
    for (int ci = 0; ci < 8; ++ci) {
      float xr[18];              // xr[row*3 + d], rows 0..5 of tile, cols c..c+2
#pragma unroll
      for (int row = 0; row < 6; ++row)
#pragma unroll
        for (int d = 0; d < 3; ++d)
          xr[row * 3 + d] = tile[(ci * 6 + row) * 72 + c + d];
#pragma unroll
      for (int ky = 0; ky < 3; ++ky)
#pragma unroll
        for (int kx = 0; kx < 3; ++kx) {
          const float* wp = &wl[(ci * 9 + ky * 3 + kx) * 64 + cog * 8];
          const float4 w0 = *(const float4*)wp;        // wave-uniform -> broadcast
          const float4 w1 = *(const float4*)(wp + 4);
#pragma unroll
          for (int j = 0; j < 4; ++j) {
            const float xv = xr[(j + ky) * 3 + kx];
            acc[0  + j] += w0.x * xv;  acc[4  + j] += w0.y * xv;
            acc[8  + j] += w0.z * xv;  acc[12 + j] += w0.w * xv;
            acc[16 + j] += w1.x * xv;  acc[20 + j] += w1.y * xv;
            acc[24 + j] += w1.z * xv;  acc[28 + j] += w1.w * xv;
          }
        }
    }
  }

#pragma unroll
  for (int o = 0; o < 8; ++o) {
    const float bv = cb[cog * 8 + o];
#pragma unroll
    for (int j = 0; j < 4; ++j) {
      out[((size_t)b * 64 + cog * 8 + o) * N_ + (size_t)(gy0 + j) * HW_ + gx0 + c]
          = acc[o * 4 + j] + bv;
    }
  }
}

// ================================================================
extern "C" void kernel_launch(void* const* d_in, const int* in_sizes, int n_in,
                              void* d_out, int out_size, void* d_ws, size_t ws_size,
                              hipStream_t stream) {
  const float* t1  = (const float*)d_in[0];
  const float* t2  = (const float*)d_in[1];
  const float* q1w = (const float*)d_in[2];
  const float* q1b = (const float*)d_in[3];
  const float* k1w = (const float*)d_in[4];
  const float* k1b = (const float*)d_in[5];
  const float* v1w = (const float*)d_in[6];
  const float* v1b = (const float*)d_in[7];
  const float* r1w = (const float*)d_in[8];
  const float* r1b = (const float*)d_in[9];
  const float* q2w = (const float*)d_in[10];
  const float* q2b = (const float*)d_in[11];
  const float* k2w = (const float*)d_in[12];
  const float* k2b = (const float*)d_in[13];
  const float* v2w = (const float*)d_in[14];
  const float* v2b = (const float*)d_in[15];
  const float* r2w = (const float*)d_in[16];
  const float* r2b = (const float*)d_in[17];
  const float* cw  = (const float*)d_in[18];
  const float* cbp = (const float*)d_in[19];
  float* out = (float*)d_out;

  char* ws = (char*)d_ws;
  const size_t catF32 = (size_t)B_ * 128 * N_ * sizeof(float);   // 256 MB
  const size_t catBF  = (size_t)B_ * 128 * N_ * 2;               // 128 MB
  const size_t partB  = (size_t)16 * CHUNKS * STATS * sizeof(float);
  const size_t derB   = (size_t)16 * STATS * sizeof(float);
  const size_t cwB    = (size_t)73728 * sizeof(float);
  const bool useF32 = ws_size >= catF32 + partB + derB + cwB;
  const size_t catBytes = useF32 ? catF32 : catBF;
  void* catp = (void*)ws;
  float* part = (float*)(ws + catBytes);
  float* der  = (float*)(ws + catBytes + partB);
  float* cwT  = (float*)(ws + catBytes + partB + derB);

  transpose_cw_kernel<<<dim3(288), 256, 0, stream>>>(cw, cwT);
  stats_kernel<<<dim3(CHUNKS, B_, 2), 256, 0, stream>>>(
      t1, t2, k1w, k1b, v1w, v1b, k2w, k2b, v2w, v2b, part);
  finalize_kernel<<<dim3(16), 256, 0, stream>>>(part, r1w, r2w, der);
  if (useF32) {
    attn_kernel<float><<<dim3(N_ / 256, B_, 2), 256, 0, stream>>>(
        t1, t2, q1w, q1b, q2w, q2b, r1b, r2b, der, (float*)catp);
    conv_kernel<float><<<dim3(4, 64, B_), 512, 0, stream>>>(
        (const float*)catp, cwT, cbp, out);
  } else {
    attn_kernel<__hip_bfloat16><<<dim3(N_ / 256, B_, 2), 256, 0, stream>>>(
        t1, t2, q1w, q1b, q2w, q2b, r1b, r2b, der, (__hip_bfloat16*)catp);
    conv_kernel<__hip_bfloat16><<<dim3(4, 64, B_), 512, 0, stream>>>(
        (const __hip_bfloat16*)catp, cwT, cbp, out);
  }
}